// Round 6
// baseline (174.930 us; speedup 1.0000x reference)
//
#include <hip/hip_runtime.h>

#define LDSP 136  // padded row stride (272B rows, 16B-aligned for b128)

typedef _Float16 h8 __attribute__((ext_vector_type(8)));
typedef _Float16 h4 __attribute__((ext_vector_type(4)));
typedef float    f4 __attribute__((ext_vector_type(4)));
typedef float    fx16 __attribute__((ext_vector_type(16)));
typedef unsigned u32x4 __attribute__((ext_vector_type(4)));

union VF { u32x4 u; h8 h; };

// lgkm-only barrier (no vmcnt drain); sched_barrier stops read hoisting (rule #18)
__device__ __forceinline__ void bar_lds() {
    asm volatile("s_waitcnt lgkmcnt(0)" ::: "memory");
    __builtin_amdgcn_s_barrier();
    __builtin_amdgcn_sched_barrier(0);
}

// pack two f32 -> one u32 of two f16 (RNE via scalar casts, matches reference rounding)
__device__ __forceinline__ unsigned pkh(float a, float b) {
    union { _Float16 h[2]; unsigned u; } t;
    t.h[0] = (_Float16)a; t.h[1] = (_Float16)b;
    return t.u;
}

// Convert one 32-row MFMA C-layout tile (rows = (r&3)+8(r>>2)+4hi) into two
// k-major B/A fragments (k = 16s+hi*8+j) via f16 pack + permlane32_swap.
// Verified numerically in round 5 (V path).  out0 = rows [0,16), out1 = [16,32).
#define PACK_TILE(av, out0, out1) {                                           \
    unsigned A0 = pkh(av[0], av[1]),   A1 = pkh(av[2], av[3]);                \
    unsigned B0 = pkh(av[4], av[5]),   B1 = pkh(av[6], av[7]);                \
    unsigned C0 = pkh(av[8], av[9]),   C1 = pkh(av[10], av[11]);              \
    unsigned D0 = pkh(av[12], av[13]), D1 = pkh(av[14], av[15]);              \
    asm volatile("v_permlane32_swap_b32 %0, %1" : "+v"(A0), "+v"(B0));        \
    asm volatile("v_permlane32_swap_b32 %0, %1" : "+v"(A1), "+v"(B1));        \
    asm volatile("v_permlane32_swap_b32 %0, %1" : "+v"(C0), "+v"(D0));        \
    asm volatile("v_permlane32_swap_b32 %0, %1" : "+v"(C1), "+v"(D1));        \
    (out0).u = (u32x4){A0, A1, B0, B1};                                       \
    (out1).u = (u32x4){C0, C1, D0, D1};                                       \
}

// ---- fused prep: Mt[f][e] = sum_d Wk[d][f]*Wq[d][e] (f16); Wvh = f16(Wv);
//      ck[f] = sum_d bq[d]*Wk[d][f].  64 blocks x 256. ----
// softmax(QK^T) == softmax(X Mt^T X^T + 1 * (ck . X^T)) -- row-constant terms drop.
__global__ void prep(const float* __restrict__ Wq, const float* __restrict__ Wk,
                     const float* __restrict__ bq, const float* __restrict__ Wv,
                     _Float16* __restrict__ Mt, _Float16* __restrict__ Wvh,
                     float* __restrict__ ck) {
    int idx = blockIdx.x * 256 + threadIdx.x;  // 16384 entries
    int e = idx & 127, f = idx >> 7;
    float a0 = 0.f, a1 = 0.f, a2 = 0.f, a3 = 0.f;
    for (int d = 0; d < 128; d += 4) {
        a0 += Wk[(d + 0) * 128 + f] * Wq[(d + 0) * 128 + e];
        a1 += Wk[(d + 1) * 128 + f] * Wq[(d + 1) * 128 + e];
        a2 += Wk[(d + 2) * 128 + f] * Wq[(d + 2) * 128 + e];
        a3 += Wk[(d + 3) * 128 + f] * Wq[(d + 3) * 128 + e];
    }
    Mt[idx]  = (_Float16)((a0 + a1) + (a2 + a3));
    Wvh[idx] = (_Float16)Wv[idx];

    if (blockIdx.x == 0 && threadIdx.x < 128) {
        int t = threadIdx.x;
        float c0 = 0.f, c1 = 0.f, c2 = 0.f, c3 = 0.f;
        for (int d = 0; d < 128; d += 4) {
            c0 += bq[d + 0] * Wk[(d + 0) * 128 + t];
            c1 += bq[d + 1] * Wk[(d + 1) * 128 + t];
            c2 += bq[d + 2] * Wk[(d + 2) * 128 + t];
            c3 += bq[d + 3] * Wk[(d + 3) * 128 + t];
        }
        ck[t] = (c0 + c1) + (c2 + c3);
    }
}

// Persistent block per CU, 4 windows, 2 barriers/window, register-resident T'/P.
// Wave v: w-tile wt = v>>1 (rows [wt*32,+32) of S/P/O), pair-half ph = v&1
// (u-half for V production, d-half {2ph,2ph+1} for PV + store).
// T' is computed REDUNDANTLY per wave (all f x own w-tile) straight into
// registers, pack-converted to k-major fragments -- no Ts buffer, no barrier.
// S covers ALL u per wave -> softmax is lane-local + one shfl_xor(32);
// P packs in-register and feeds PV's A operand directly. Only V crosses waves.
__global__ __launch_bounds__(512, 2) void attn(
    const float* __restrict__ x, const _Float16* __restrict__ Mt,
    const _Float16* __restrict__ Wvh, const float* __restrict__ ck,
    const float* __restrict__ bv, float* __restrict__ out) {
    __shared__ _Float16 Xs[2][128 * LDSP];  // X (f16), double-buffered
    __shared__ _Float16 Vs[128 * LDSP];     // V transposed: Vs[d][u]

    const int tid  = threadIdx.x;
    const int wv   = tid >> 6;
    const int lane = tid & 63;
    const int l32  = lane & 31;
    const int hi   = lane >> 5;
    const int wt   = wv >> 1;  // w-tile (S/P/O rows), d-strip (V production)
    const int ph   = wv & 1;   // u-half (V production), d-half pair (PV/store)

    const float bvv = bv[wt * 32 + l32];
    const size_t base0 = (size_t)blockIdx.x * 4 * (128 * 128);

    // prefetch window 0 into registers
    f4 pf[8];
#pragma unroll
    for (int j = 0; j < 8; ++j)
        pf[j] = *(const f4*)(x + base0 + 4 * tid + 2048 * j);

    for (int it = 0; it < 4; ++it) {
        _Float16* X = Xs[it & 1];

        // ---- stage: convert prefetched regs -> X (f16 LDS) ----
#pragma unroll
        for (int j = 0; j < 8; ++j) {
            int idx = 4 * tid + 2048 * j;
            int row = idx >> 7, col = idx & 127;
            f4 f = pf[j];
            h4 h = {(_Float16)f.x, (_Float16)f.y, (_Float16)f.z, (_Float16)f.w};
            *(h4*)(&X[row * LDSP + col]) = h;
        }
        // issue next-window prefetch (stays in flight across both barriers)
        if (it < 3) {
            const float* nx = x + base0 + (size_t)(it + 1) * (128 * 128);
#pragma unroll
            for (int j = 0; j < 8; ++j)
                pf[j] = *(const f4*)(nx + 4 * tid + 2048 * j);
        }
        bar_lds();  // B1: X ready (also fences prev window's Vs readers vs writers)

        // ---- V: V[u][d] = sum_e X[u][e] Wvh[d][e] + bv[d]; u-half ph, d-strip wt ----
        {
            fx16 av0, av1;
#pragma unroll
            for (int r = 0; r < 16; ++r) av0[r] = bvv;
            av1 = av0;
#pragma unroll
            for (int e0 = 0; e0 < 8; ++e0) {
                h8 wf = *(const h8*)(Wvh + (wt * 32 + l32) * 128 + e0 * 16 + hi * 8);
                h8 x0 = *(const h8*)(&X[((2 * ph) * 32 + l32) * LDSP + e0 * 16 + hi * 8]);
                h8 x1 = *(const h8*)(&X[((2 * ph + 1) * 32 + l32) * LDSP + e0 * 16 + hi * 8]);
                av0 = __builtin_amdgcn_mfma_f32_32x32x16_f16(x0, wf, av0, 0, 0, 0);
                av1 = __builtin_amdgcn_mfma_f32_32x32x16_f16(x1, wf, av1, 0, 0, 0);
            }
            // C: col d = wt*32+l32, row u = ut*32+(r&3)+8(r>>2)+4hi -> Vs[d][u]
#pragma unroll
            for (int run = 0; run < 4; ++run) {
                h4 g0 = {(_Float16)av0[run * 4 + 0], (_Float16)av0[run * 4 + 1],
                         (_Float16)av0[run * 4 + 2], (_Float16)av0[run * 4 + 3]};
                *(h4*)(&Vs[(wt * 32 + l32) * LDSP + (2 * ph) * 32 + run * 8 + 4 * hi]) = g0;
                h4 g1 = {(_Float16)av1[run * 4 + 0], (_Float16)av1[run * 4 + 1],
                         (_Float16)av1[run * 4 + 2], (_Float16)av1[run * 4 + 3]};
                *(h4*)(&Vs[(wt * 32 + l32) * LDSP + (2 * ph + 1) * 32 + run * 8 + 4 * hi]) = g1;
            }
        }

        // ---- T' (register-resident, redundant per pair): all f x own w-tile ----
        // T'[f][w] = sum_e Mt[f][e] X[w][e] + ck[f];  A = Mt (global, L2-hot),
        // B = X rows [wt*32,+32).  C rows = f -> PACK to k-major frags tfr[f0].
        VF tfr[8];
        {
            h8 bx[8];
#pragma unroll
            for (int e0 = 0; e0 < 8; ++e0)
                bx[e0] = *(const h8*)(&X[(wt * 32 + l32) * LDSP + e0 * 16 + hi * 8]);
#pragma unroll
            for (int ft = 0; ft < 4; ++ft) {
                fx16 a;
#pragma unroll
                for (int run = 0; run < 4; ++run) {
                    f4 c = *(const f4*)(ck + ft * 32 + run * 8 + 4 * hi);
                    a[run * 4 + 0] = c.x; a[run * 4 + 1] = c.y;
                    a[run * 4 + 2] = c.z; a[run * 4 + 3] = c.w;
                }
#pragma unroll
                for (int e0 = 0; e0 < 8; ++e0) {
                    h8 mt = *(const h8*)(Mt + (ft * 32 + l32) * 128 + e0 * 16 + hi * 8);
                    a = __builtin_amdgcn_mfma_f32_32x32x16_f16(mt, bx[e0], a, 0, 0, 0);
                }
                PACK_TILE(a, tfr[2 * ft], tfr[2 * ft + 1]);
            }
        }
        bar_lds();  // B2: Vs ready (T' already in registers)

        // ---- S[u][w] = sum_f X[u][f] T'[w][f]; ALL u, own w-tile ----
        fx16 su[4];
#pragma unroll
        for (int ut = 0; ut < 4; ++ut)
#pragma unroll
            for (int r = 0; r < 16; ++r) su[ut][r] = 0.f;
#pragma unroll
        for (int f0 = 0; f0 < 8; ++f0) {
#pragma unroll
            for (int ut = 0; ut < 4; ++ut) {
                h8 ax = *(const h8*)(&X[(ut * 32 + l32) * LDSP + f0 * 16 + hi * 8]);
                su[ut] = __builtin_amdgcn_mfma_f32_32x32x16_f16(ax, tfr[f0].h, su[ut], 0, 0, 0);
            }
        }

        // ---- softmax over u for col w = wt*32+l32: 64 values/lane + hi-merge ----
        float m0 = -1e30f, m1 = -1e30f;
#pragma unroll
        for (int ut = 0; ut < 4; ++ut)
#pragma unroll
            for (int r = 0; r < 16; r += 2) {
                m0 = fmaxf(m0, su[ut][r]);
                m1 = fmaxf(m1, su[ut][r + 1]);
            }
        float m = fmaxf(m0, m1);
        m = fmaxf(m, __shfl_xor(m, 32, 64));
        float s0 = 0.f, s1 = 0.f;
#pragma unroll
        for (int ut = 0; ut < 4; ++ut)
#pragma unroll
            for (int r = 0; r < 16; r += 2) {
                su[ut][r]     = __expf(su[ut][r] - m);
                su[ut][r + 1] = __expf(su[ut][r + 1] - m);
                s0 += su[ut][r];
                s1 += su[ut][r + 1];
            }
        float ss = s0 + s1;
        ss += __shfl_xor(ss, 32, 64);
        float inv = 1.0f / ss;
        // P = su * inv, packed to k-major A-fragments (rows u -> k = u)
        VF pfr[8];
#pragma unroll
        for (int ut = 0; ut < 4; ++ut) {
            fx16 p;
#pragma unroll
            for (int r = 0; r < 16; ++r) p[r] = su[ut][r] * inv;
            PACK_TILE(p, pfr[2 * ut], pfr[2 * ut + 1]);
        }

        // ---- PV: O[w][d] = sum_u P[w][u] V[u][d]; own w-tile, d-tiles {2ph,2ph+1} ----
        fx16 o0, o1;
#pragma unroll
        for (int r = 0; r < 16; ++r) o0[r] = 0.f;
        o1 = o0;
#pragma unroll
        for (int u0 = 0; u0 < 8; ++u0) {
            h8 v0 = *(const h8*)(&Vs[((2 * ph) * 32 + l32) * LDSP + u0 * 16 + hi * 8]);
            h8 v1 = *(const h8*)(&Vs[((2 * ph + 1) * 32 + l32) * LDSP + u0 * 16 + hi * 8]);
            o0 = __builtin_amdgcn_mfma_f32_32x32x16_f16(pfr[u0].h, v0, o0, 0, 0, 0);
            o1 = __builtin_amdgcn_mfma_f32_32x32x16_f16(pfr[u0].h, v1, o1, 0, 0, 0);
        }
        // C: col d = dt*32+l32, row w = wt*32+(r&3)+8(r>>2)+4hi; coalesced 128B runs.
        // Stores never vmcnt-waited in the loop -> drain under next window.
        float* ob = out + base0 + (size_t)it * (128 * 128);
#pragma unroll
        for (int r = 0; r < 16; ++r) {
            int wrow = wt * 32 + (r & 3) + 8 * (r >> 2) + 4 * hi;
            ob[(size_t)wrow * 128 + (2 * ph) * 32 + l32]     = o0[r];
            ob[(size_t)wrow * 128 + (2 * ph + 1) * 32 + l32] = o1[r];
        }
    }
}

extern "C" void kernel_launch(void* const* d_in, const int* in_sizes, int n_in,
                              void* d_out, int out_size, void* d_ws, size_t ws_size,
                              hipStream_t stream) {
    const float* x  = (const float*)d_in[0];
    const float* Wq = (const float*)d_in[1];
    const float* bq = (const float*)d_in[2];
    const float* Wk = (const float*)d_in[3];
    // bk (d_in[4]) drops out of softmax entirely
    const float* Wv = (const float*)d_in[5];
    const float* bv = (const float*)d_in[6];

    _Float16* Mt  = (_Float16*)d_ws;        // 32 KiB
    _Float16* Wvh = Mt + 16384;             // 32 KiB
    float*    ckp = (float*)(Wvh + 16384);  // 512 B

    prep<<<64, 256, 0, stream>>>(Wq, Wk, bq, Wv, Mt, Wvh, ckp);
    attn<<<256, 512, 0, stream>>>(x, Mt, Wvh, ckp, bv, (float*)d_out);
}